// Round 7
// baseline (198.304 us; speedup 1.0000x reference)
//
#include <hip/hip_runtime.h>
#include <hip/hip_bf16.h>
#include <math.h>

// Problem constants (B=1)
#define S_LEN   2048
#define DM      1024
#define NH      16
#define DH      64
#define WIN     256

typedef __attribute__((ext_vector_type(8))) short          bf16x8;
typedef __attribute__((ext_vector_type(4))) float          f32x4;
typedef __attribute__((ext_vector_type(8))) unsigned short u16x8;
typedef __attribute__((ext_vector_type(4))) unsigned short u16x4;
typedef unsigned short u16;

// async global->LDS, 16B per lane, linear LDS dest (wave-uniform base + lane*16)
#define GLDS(gsrc, ldst)                                                        \
    __builtin_amdgcn_global_load_lds(                                           \
        (const __attribute__((address_space(1))) void*)(gsrc),                  \
        (__attribute__((address_space(3))) void*)(ldst), 16, 0, 0)

// fp32 -> bf16 round-to-nearest-even (finite inputs only)
__device__ __forceinline__ u16 f2bf(float f) {
    union { float f; unsigned u; } v; v.f = f;
    unsigned r = v.u + 0x7FFF + ((v.u >> 16) & 1);
    return (u16)(r >> 16);
}

// ---------------------------------------------------------------------------
// Pre-pass 1: x fp32 -> bf16 (row-major [2048][1024])
// ---------------------------------------------------------------------------
__global__ __launch_bounds__(256) void cvt_x_kernel(const float* __restrict__ x,
                                                    u16* __restrict__ xb) {
    int i = (blockIdx.x * 256 + threadIdx.x) * 8;
    float4 a = *(const float4*)&x[i];
    float4 b = *(const float4*)&x[i + 4];
    u16x8 o;
    o[0] = f2bf(a.x); o[1] = f2bf(a.y); o[2] = f2bf(a.z); o[3] = f2bf(a.w);
    o[4] = f2bf(b.x); o[5] = f2bf(b.y); o[6] = f2bf(b.z); o[7] = f2bf(b.w);
    *(u16x8*)&xb[i] = o;
}

// ---------------------------------------------------------------------------
// Pre-pass 2: W fp32 [K=in][N=out] -> Wt bf16 [N][K]  (z picks Wq/Wk/Wv/Wo)
// ---------------------------------------------------------------------------
__global__ __launch_bounds__(256) void cvt_wT_kernel(const float* __restrict__ Wq,
                                                     const float* __restrict__ Wk,
                                                     const float* __restrict__ Wv,
                                                     const float* __restrict__ Wo,
                                                     u16* __restrict__ WT) {
    __shared__ float Ws[64][65];
    const float* W = (blockIdx.z == 0) ? Wq : (blockIdx.z == 1) ? Wk
                   : (blockIdx.z == 2) ? Wv : Wo;
    u16* dst = WT + (size_t)blockIdx.z * (1u << 20);
    const int k0 = blockIdx.x * 64, n0 = blockIdx.y * 64;
    const int tid = threadIdx.x;
#pragma unroll
    for (int p = 0; p < 4; ++p) {
        int flat = tid + p * 256;
        int row = flat >> 4, c4 = (flat & 15) * 4;      // row = k index
        float4 v = *(const float4*)&W[(k0 + row) * DM + n0 + c4];
        Ws[row][c4 + 0] = v.x; Ws[row][c4 + 1] = v.y;
        Ws[row][c4 + 2] = v.z; Ws[row][c4 + 3] = v.w;
    }
    __syncthreads();
#pragma unroll
    for (int p = 0; p < 4; ++p) {
        int flat = tid + p * 256;
        int n = flat >> 4, k4 = (flat & 15) * 4;
        u16x4 o;
#pragma unroll
        for (int j = 0; j < 4; ++j) o[j] = f2bf(Ws[k4 + j][n]);
        *(u16x4*)&dst[(n0 + n) * DM + k0 + k4] = o;
    }
}

// ---------------------------------------------------------------------------
// bf16 MFMA GEMM: C[2048][1024] = A @ Bt^T + bias
// BM=64, BN=128, BK=64; 4 waves (2x2: 32x64 each); acc 2x4 frags 16x16x32.
// Staging via global_load_lds width=16: linear LDS dest, PRE-SWIZZLED global
// source (lane chunk g = (l&7)^(l>>3)); frag reads XOR-unswizzle -> <=2-way.
// OMODE: 0 = bf16 row-major, 1 = f32 row-major, 2 = bf16 transposed into
// VT[col][token] (fuses the V-transpose into the epilogue; 4 acc rows are
// contiguous tokens -> aligned u16x4 store).
// ---------------------------------------------------------------------------
template<int OMODE>
__device__ __forceinline__ void gemm_mfma_body(const u16* __restrict__ A,
                                               const u16* __restrict__ Bt,
                                               const float* __restrict__ bias,
                                               u16* __restrict__ Cb,
                                               float* __restrict__ Cf) {
    __shared__ __align__(16) u16 As[64 * 64];    // 8 KB
    __shared__ __align__(16) u16 Bs[128 * 64];   // 16 KB
    const int tid = threadIdx.x;
    const int l = tid & 63, w = tid >> 6;
    const int wm = w >> 1, wn = w & 1;
    const int l15 = l & 15, lh = l >> 4;
    const int brow = blockIdx.y * 64, bcol = blockIdx.x * 128;

    f32x4 acc[2][4];
#pragma unroll
    for (int i = 0; i < 2; ++i)
#pragma unroll
        for (int j = 0; j < 4; ++j) acc[i][j] = (f32x4)0.f;

    // per-lane staging source (element offsets); row % 8 == lr always
    const int lr = l >> 3, lc = l & 7, g = lc ^ lr;
    const u16* aSrc = A  + (size_t)(brow + w * 16 + lr) * DM + g * 8;
    const u16* bSrc = Bt + (size_t)(bcol + w * 32 + lr) * DM + g * 8;

    for (int k0 = 0; k0 < DM; k0 += 64) {
        __syncthreads();
#pragma unroll
        for (int i = 0; i < 2; ++i)
            GLDS(aSrc + i * 8 * DM + k0, &As[(w * 2 + i) * 512]);
#pragma unroll
        for (int i = 0; i < 4; ++i)
            GLDS(bSrc + i * 8 * DM + k0, &Bs[(w * 4 + i) * 512]);
        __syncthreads();   // compiler drains vmcnt before barrier

#pragma unroll
        for (int ks = 0; ks < 2; ++ks) {
            bf16x8 af[2], bf[4];
#pragma unroll
            for (int i = 0; i < 2; ++i) {
                int ra = wm * 32 + i * 16 + l15;
                af[i] = *(const bf16x8*)&As[ra * 64 + (((ks * 4 + lh) ^ (ra & 7)) * 8)];
            }
#pragma unroll
            for (int j = 0; j < 4; ++j) {
                int rb = wn * 64 + j * 16 + l15;
                bf[j] = *(const bf16x8*)&Bs[rb * 64 + (((ks * 4 + lh) ^ (rb & 7)) * 8)];
            }
#pragma unroll
            for (int i = 0; i < 2; ++i)
#pragma unroll
                for (int j = 0; j < 4; ++j)
                    acc[i][j] = __builtin_amdgcn_mfma_f32_16x16x32_bf16(af[i], bf[j], acc[i][j], 0, 0, 0);
        }
    }
    // epilogue: D frag layout row=lh*4+rr, col=l15
#pragma unroll
    for (int j = 0; j < 4; ++j) {
        int gcol = bcol + wn * 64 + j * 16 + l15;
        float bz = bias[gcol];
#pragma unroll
        for (int i = 0; i < 2; ++i) {
            int grow = brow + wm * 32 + i * 16 + lh * 4;
            if (OMODE == 2) {
                u16x4 tv;
#pragma unroll
                for (int rr = 0; rr < 4; ++rr) tv[rr] = f2bf(acc[i][j][rr] + bz);
                *(u16x4*)&Cb[(size_t)gcol * S_LEN + grow] = tv;   // VT[col][token]
            } else {
#pragma unroll
                for (int rr = 0; rr < 4; ++rr) {
                    float v = acc[i][j][rr] + bz;
                    if (OMODE == 0) Cb[(grow + rr) * DM + gcol] = f2bf(v);
                    else            Cf[(grow + rr) * DM + gcol] = v;
                }
            }
        }
    }
}

__global__ __launch_bounds__(256) void qkv_mfma_kernel(
        const u16* __restrict__ xb,
        const u16* __restrict__ WqT, const float* __restrict__ bq, u16* __restrict__ Qb,
        const u16* __restrict__ WkT, const float* __restrict__ bk, u16* __restrict__ Kb,
        const u16* __restrict__ WvT, const float* __restrict__ bv, u16* __restrict__ VT) {
    if (blockIdx.z == 0)      gemm_mfma_body<0>(xb, WqT, bq, Qb, nullptr);
    else if (blockIdx.z == 1) gemm_mfma_body<0>(xb, WkT, bk, Kb, nullptr);
    else                      gemm_mfma_body<2>(xb, WvT, bv, VT, nullptr);
}

__global__ __launch_bounds__(256) void oproj_mfma_kernel(
        const u16* __restrict__ Ob, const u16* __restrict__ WoT,
        const float* __restrict__ bo, float* __restrict__ out) {
    gemm_mfma_body<1>(Ob, WoT, bo, nullptr, out);
}

// ---------------------------------------------------------------------------
// MFMA flash attention, NO-MAX softmax, KV-SPLIT x2.
// Block = (32 Q rows, head), 4 waves: wave pair (qg, half) -> 16 rows each,
// half of the tile list each. Partials (unnormalized O, lane-local row sums)
// merge by pure addition via LDS + one barrier. Grid 1024 blocks -> 4 w/SIMD.
// ---------------------------------------------------------------------------
__global__ __launch_bounds__(256, 4) void attn_mfma_kernel(
        const u16* __restrict__ Qb, const u16* __restrict__ Kb,
        const u16* __restrict__ VT, u16* __restrict__ Ob) {
    __shared__ __align__(16) u16 Pl[4 * 16 * 72];     // per-wave P, 9 KB
    __shared__ __align__(16) float MB[2][64][20];     // merge buf, 10 KB
    const int tid = threadIdx.x;
    const int w = tid >> 6, l = tid & 63;
    const int qg = w >> 1, half = w & 1;
    const int l15 = l & 15, lh = l >> 4;
    const int i0 = blockIdx.x * 32, h = blockIdx.y;
    const int q0 = i0 + qg * 16;
    u16* Pw = &Pl[w * 16 * 72];

    // Q A-frags: lane row l15, chunk ks*32 + lh*8
    bf16x8 qf[2];
    {
        int qr = q0 + l15;
        qf[0] = *(const bf16x8*)&Qb[qr * DM + h * DH + lh * 8];
        qf[1] = *(const bf16x8*)&Qb[qr * DM + h * DH + 32 + lh * 8];
    }

    f32x4 o[4];
    float ls[4] = {0.f, 0.f, 0.f, 0.f};
#pragma unroll
    for (int fc = 0; fc < 4; ++fc) o[fc] = (f32x4)0.f;

    // tile list for this 16-row group: band tiles + global tile 0 (iff t_lo>0)
    int t_lo, t_hi;
    {
        int lo = q0 - WIN;      if (lo < 0) lo = 0;
        int hi = q0 + 15 + WIN; if (hi > S_LEN - 1) hi = S_LEN - 1;
        if (q0 == 0) hi = S_LEN - 1;          // global row 0: all tiles
        t_lo = lo >> 6; t_hi = hi >> 6;
    }
    const int nband = t_hi - t_lo + 1;
    const int nt = nband + (t_lo > 0 ? 1 : 0);
    // this wave's half of the list
    const int b0 = half ? ((nt + 1) >> 1) : 0;
    const int b1 = half ? nt : ((nt + 1) >> 1);

    // K-frag preload for first tile of this half
    bf16x8 kf[2][4];
    if (b0 < b1) {
        const int j0 = ((b0 < nband) ? (t_lo + b0) : 0) << 6;
#pragma unroll
        for (int ks = 0; ks < 2; ++ks)
#pragma unroll
            for (int fc = 0; fc < 4; ++fc)
                kf[ks][fc] = *(const bf16x8*)&Kb[(j0 + fc * 16 + l15) * DM + h * DH + ks * 32 + lh * 8];
    }

    for (int it = b0; it < b1; ++it) {
        const int j0 = ((it < nband) ? (t_lo + it) : 0) << 6;

        // V-frags for current tile (consumed after exp -> latency covered)
        bf16x8 vf[2][4];
#pragma unroll
        for (int ks = 0; ks < 2; ++ks)
#pragma unroll
            for (int fc = 0; fc < 4; ++fc)
                vf[ks][fc] = *(const bf16x8*)&VT[(h * DH + fc * 16 + l15) * S_LEN + j0 + ks * 32 + lh * 8];

        // S = Q K^T
        f32x4 s[4];
#pragma unroll
        for (int fc = 0; fc < 4; ++fc) s[fc] = (f32x4)0.f;
#pragma unroll
        for (int ks = 0; ks < 2; ++ks)
#pragma unroll
            for (int fc = 0; fc < 4; ++fc)
                s[fc] = __builtin_amdgcn_mfma_f32_16x16x32_bf16(qf[ks], kf[ks][fc], s[fc], 0, 0, 0);

        // prefetch next tile's K-frags (last iter: reload current, unused)
        const int itn = (it + 1 < b1) ? it + 1 : it;
        const int jn = ((itn < nband) ? (t_lo + itn) : 0) << 6;
        bf16x8 kn[2][4];
#pragma unroll
        for (int ks = 0; ks < 2; ++ks)
#pragma unroll
            for (int fc = 0; fc < 4; ++fc)
                kn[ks][fc] = *(const bf16x8*)&Kb[(jn + fc * 16 + l15) * DM + h * DH + ks * 32 + lh * 8];

        // mask + exp (no max-sub); lane-local row-sum accumulate
#pragma unroll
        for (int fc = 0; fc < 4; ++fc)
#pragma unroll
            for (int rr = 0; rr < 4; ++rr) {
                int r = q0 + lh * 4 + rr;
                int c = j0 + fc * 16 + l15;
                int d = r - c;
                bool ok = (d <= WIN && -d <= WIN) || (r == 0) || (c == 0);
                s[fc][rr] = ok ? __expf(s[fc][rr] * 0.125f) : 0.f;
            }
#pragma unroll
        for (int rr = 0; rr < 4; ++rr)
            ls[rr] += (s[0][rr] + s[1][rr]) + (s[2][rr] + s[3][rr]);

        // P -> wave-private LDS as bf16 [qrow16][kv64], pitch 72
#pragma unroll
        for (int fc = 0; fc < 4; ++fc)
#pragma unroll
            for (int rr = 0; rr < 4; ++rr)
                Pw[(lh * 4 + rr) * 72 + fc * 16 + l15] = f2bf(s[fc][rr]);
        asm volatile("s_waitcnt lgkmcnt(0)" ::: "memory");

        // O += P V
#pragma unroll
        for (int ks = 0; ks < 2; ++ks) {
            bf16x8 pa = *(const bf16x8*)&Pw[l15 * 72 + ks * 32 + lh * 8];
#pragma unroll
            for (int fc = 0; fc < 4; ++fc)
                o[fc] = __builtin_amdgcn_mfma_f32_16x16x32_bf16(pa, vf[ks][fc], o[fc], 0, 0, 0);
        }

        // rotate prefetched K into place
#pragma unroll
        for (int ks = 0; ks < 2; ++ks)
#pragma unroll
            for (int fc = 0; fc < 4; ++fc)
                kf[ks][fc] = kn[ks][fc];
    }

    // merge halves: half=1 publishes partials, half=0 adds and writes output
    if (half == 1) {
#pragma unroll
        for (int fc = 0; fc < 4; ++fc)
            *(f32x4*)&MB[qg][l][fc * 4] = o[fc];
        *(f32x4*)&MB[qg][l][16] = (f32x4){ls[0], ls[1], ls[2], ls[3]};
    }
    __syncthreads();
    if (half == 0) {
#pragma unroll
        for (int fc = 0; fc < 4; ++fc) {
            f32x4 po = *(const f32x4*)&MB[qg][l][fc * 4];
            o[fc] += po;
        }
        f32x4 pl = *(const f32x4*)&MB[qg][l][16];
#pragma unroll
        for (int rr = 0; rr < 4; ++rr) ls[rr] += pl[rr];

        // single cross-lane reduce of row sums (within each 16-lane lh group)
#pragma unroll
        for (int rr = 0; rr < 4; ++rr)
#pragma unroll
            for (int mk = 1; mk < 16; mk <<= 1)
                ls[rr] += __shfl_xor(ls[rr], mk, 64);

#pragma unroll
        for (int rr = 0; rr < 4; ++rr) {
            float inv = 1.0f / ls[rr];
#pragma unroll
            for (int fc = 0; fc < 4; ++fc)
                Ob[(q0 + lh * 4 + rr) * DM + h * DH + fc * 16 + l15] = f2bf(o[fc][rr] * inv);
        }
    }
}

// ---------------------------------------------------------------------------
extern "C" void kernel_launch(void* const* d_in, const int* in_sizes, int n_in,
                              void* d_out, int out_size, void* d_ws, size_t ws_size,
                              hipStream_t stream) {
    const float* x  = (const float*)d_in[0];
    const float* Wq = (const float*)d_in[1];
    const float* bq = (const float*)d_in[2];
    const float* Wk = (const float*)d_in[3];
    const float* bk = (const float*)d_in[4];
    const float* Wv = (const float*)d_in[5];
    const float* bv = (const float*)d_in[6];
    const float* Wo = (const float*)d_in[7];
    const float* bo = (const float*)d_in[8];
    float* out = (float*)d_out;

    char* W = (char*)d_ws;
    u16* xb  = (u16*)(W);                        // 4 MB  (reused as Ob after qkv)
    u16* WT  = (u16*)(W + ((size_t)4  << 20));   // 4 x 2 MB = 8 MB
    u16* Qb  = (u16*)(W + ((size_t)12 << 20));   // 4 MB
    u16* Kb  = (u16*)(W + ((size_t)16 << 20));   // 4 MB
    u16* VT  = (u16*)(W + ((size_t)20 << 20));   // 4 MB   (total 24 MB)
    u16* Ob  = xb;                               // x dead after qkv
    const u16* WqT = WT;
    const u16* WkT = WT + (1u << 20);
    const u16* WvT = WT + (2u << 20);
    const u16* WoT = WT + (3u << 20);

    cvt_x_kernel <<<dim3(S_LEN * DM / (256 * 8)), 256, 0, stream>>>(x, xb);
    cvt_wT_kernel<<<dim3(16, 16, 4), 256, 0, stream>>>(Wq, Wk, Wv, Wo, WT);
    qkv_mfma_kernel<<<dim3(8, 32, 3), 256, 0, stream>>>(xb, WqT, bq, Qb,
                                                        WkT, bk, Kb, WvT, bv, VT);
    attn_mfma_kernel<<<dim3(64, 16), 256, 0, stream>>>(Qb, Kb, VT, Ob);
    oproj_mfma_kernel<<<dim3(8, 32), 256, 0, stream>>>(Ob, WoT, bo, out);
}

// Round 11
// 168.789 us; speedup vs baseline: 1.1749x; 1.1749x over previous
//
#include <hip/hip_runtime.h>
#include <hip/hip_bf16.h>
#include <math.h>

// Problem constants (B=1)
#define S_LEN   2048
#define DM      1024
#define NH      16
#define DH      64
#define WIN     256

typedef __attribute__((ext_vector_type(8))) short          bf16x8;
typedef __attribute__((ext_vector_type(4))) float          f32x4;
typedef __attribute__((ext_vector_type(8))) unsigned short u16x8;
typedef __attribute__((ext_vector_type(4))) unsigned short u16x4;
typedef unsigned short u16;

// async global->LDS, 16B per lane, linear LDS dest (wave-uniform base + lane*16)
#define GLDS(gsrc, ldst)                                                        \
    __builtin_amdgcn_global_load_lds(                                           \
        (const __attribute__((address_space(1))) void*)(gsrc),                  \
        (__attribute__((address_space(3))) void*)(ldst), 16, 0, 0)

// fp32 -> bf16 round-to-nearest-even (finite inputs only)
__device__ __forceinline__ u16 f2bf(float f) {
    union { float f; unsigned u; } v; v.f = f;
    unsigned r = v.u + 0x7FFF + ((v.u >> 16) & 1);
    return (u16)(r >> 16);
}

// ---------------------------------------------------------------------------
// Pre-pass 1: x fp32 -> bf16 (row-major [2048][1024])
// ---------------------------------------------------------------------------
__global__ __launch_bounds__(256) void cvt_x_kernel(const float* __restrict__ x,
                                                    u16* __restrict__ xb) {
    int i = (blockIdx.x * 256 + threadIdx.x) * 8;
    float4 a = *(const float4*)&x[i];
    float4 b = *(const float4*)&x[i + 4];
    u16x8 o;
    o[0] = f2bf(a.x); o[1] = f2bf(a.y); o[2] = f2bf(a.z); o[3] = f2bf(a.w);
    o[4] = f2bf(b.x); o[5] = f2bf(b.y); o[6] = f2bf(b.z); o[7] = f2bf(b.w);
    *(u16x8*)&xb[i] = o;
}

// ---------------------------------------------------------------------------
// Pre-pass 2: W fp32 [K=in][N=out] -> Wt bf16 [N][K]  (z picks Wq/Wk/Wv/Wo)
// ---------------------------------------------------------------------------
__global__ __launch_bounds__(256) void cvt_wT_kernel(const float* __restrict__ Wq,
                                                     const float* __restrict__ Wk,
                                                     const float* __restrict__ Wv,
                                                     const float* __restrict__ Wo,
                                                     u16* __restrict__ WT) {
    __shared__ float Ws[64][65];
    const float* W = (blockIdx.z == 0) ? Wq : (blockIdx.z == 1) ? Wk
                   : (blockIdx.z == 2) ? Wv : Wo;
    u16* dst = WT + (size_t)blockIdx.z * (1u << 20);
    const int k0 = blockIdx.x * 64, n0 = blockIdx.y * 64;
    const int tid = threadIdx.x;
#pragma unroll
    for (int p = 0; p < 4; ++p) {
        int flat = tid + p * 256;
        int row = flat >> 4, c4 = (flat & 15) * 4;      // row = k index
        float4 v = *(const float4*)&W[(k0 + row) * DM + n0 + c4];
        Ws[row][c4 + 0] = v.x; Ws[row][c4 + 1] = v.y;
        Ws[row][c4 + 2] = v.z; Ws[row][c4 + 3] = v.w;
    }
    __syncthreads();
#pragma unroll
    for (int p = 0; p < 4; ++p) {
        int flat = tid + p * 256;
        int n = flat >> 4, k4 = (flat & 15) * 4;
        u16x4 o;
#pragma unroll
        for (int j = 0; j < 4; ++j) o[j] = f2bf(Ws[k4 + j][n]);
        *(u16x4*)&dst[(n0 + n) * DM + k0 + k4] = o;
    }
}

// ---------------------------------------------------------------------------
// bf16 MFMA GEMM: C[2048][1024] = A @ Bt^T + bias
// BM=64, BN=128, BK=64; 4 waves (2x2: 32x64 each); acc 2x4 frags 16x16x32.
// Staging via global_load_lds width=16: linear LDS dest, PRE-SWIZZLED global
// source (lane chunk g = (l&7)^(l>>3)); frag reads XOR-unswizzle -> <=2-way.
// OMODE: 0 = bf16 row-major, 1 = f32 row-major, 2 = bf16 transposed into
// VT[col][token] (fuses the V-transpose into the epilogue).
// ---------------------------------------------------------------------------
template<int OMODE>
__device__ __forceinline__ void gemm_mfma_body(const u16* __restrict__ A,
                                               const u16* __restrict__ Bt,
                                               const float* __restrict__ bias,
                                               u16* __restrict__ Cb,
                                               float* __restrict__ Cf) {
    __shared__ __align__(16) u16 As[64 * 64];    // 8 KB
    __shared__ __align__(16) u16 Bs[128 * 64];   // 16 KB
    const int tid = threadIdx.x;
    const int l = tid & 63, w = tid >> 6;
    const int wm = w >> 1, wn = w & 1;
    const int l15 = l & 15, lh = l >> 4;
    const int brow = blockIdx.y * 64, bcol = blockIdx.x * 128;

    f32x4 acc[2][4];
#pragma unroll
    for (int i = 0; i < 2; ++i)
#pragma unroll
        for (int j = 0; j < 4; ++j) acc[i][j] = (f32x4)0.f;

    // per-lane staging source (element offsets); row % 8 == lr always
    const int lr = l >> 3, lc = l & 7, g = lc ^ lr;
    const u16* aSrc = A  + (size_t)(brow + w * 16 + lr) * DM + g * 8;
    const u16* bSrc = Bt + (size_t)(bcol + w * 32 + lr) * DM + g * 8;

    for (int k0 = 0; k0 < DM; k0 += 64) {
        __syncthreads();
#pragma unroll
        for (int i = 0; i < 2; ++i)
            GLDS(aSrc + i * 8 * DM + k0, &As[(w * 2 + i) * 512]);
#pragma unroll
        for (int i = 0; i < 4; ++i)
            GLDS(bSrc + i * 8 * DM + k0, &Bs[(w * 4 + i) * 512]);
        __syncthreads();   // compiler drains vmcnt before barrier

#pragma unroll
        for (int ks = 0; ks < 2; ++ks) {
            bf16x8 af[2], bf[4];
#pragma unroll
            for (int i = 0; i < 2; ++i) {
                int ra = wm * 32 + i * 16 + l15;
                af[i] = *(const bf16x8*)&As[ra * 64 + (((ks * 4 + lh) ^ (ra & 7)) * 8)];
            }
#pragma unroll
            for (int j = 0; j < 4; ++j) {
                int rb = wn * 64 + j * 16 + l15;
                bf[j] = *(const bf16x8*)&Bs[rb * 64 + (((ks * 4 + lh) ^ (rb & 7)) * 8)];
            }
#pragma unroll
            for (int i = 0; i < 2; ++i)
#pragma unroll
                for (int j = 0; j < 4; ++j)
                    acc[i][j] = __builtin_amdgcn_mfma_f32_16x16x32_bf16(af[i], bf[j], acc[i][j], 0, 0, 0);
        }
    }
    // epilogue: D frag layout row=lh*4+rr, col=l15
#pragma unroll
    for (int j = 0; j < 4; ++j) {
        int gcol = bcol + wn * 64 + j * 16 + l15;
        float bz = bias[gcol];
#pragma unroll
        for (int i = 0; i < 2; ++i) {
            int grow = brow + wm * 32 + i * 16 + lh * 4;
            if (OMODE == 2) {
                u16x4 tv;
#pragma unroll
                for (int rr = 0; rr < 4; ++rr) tv[rr] = f2bf(acc[i][j][rr] + bz);
                *(u16x4*)&Cb[(size_t)gcol * S_LEN + grow] = tv;   // VT[col][token]
            } else {
#pragma unroll
                for (int rr = 0; rr < 4; ++rr) {
                    float v = acc[i][j][rr] + bz;
                    if (OMODE == 0) Cb[(grow + rr) * DM + gcol] = f2bf(v);
                    else            Cf[(grow + rr) * DM + gcol] = v;
                }
            }
        }
    }
}

__global__ __launch_bounds__(256) void qkv_mfma_kernel(
        const u16* __restrict__ xb,
        const u16* __restrict__ WqT, const float* __restrict__ bq, u16* __restrict__ Qb,
        const u16* __restrict__ WkT, const float* __restrict__ bk, u16* __restrict__ Kb,
        const u16* __restrict__ WvT, const float* __restrict__ bv, u16* __restrict__ VT) {
    if (blockIdx.z == 0)      gemm_mfma_body<0>(xb, WqT, bq, Qb, nullptr);
    else if (blockIdx.z == 1) gemm_mfma_body<0>(xb, WkT, bk, Kb, nullptr);
    else                      gemm_mfma_body<2>(xb, WvT, bv, VT, nullptr);
}

__global__ __launch_bounds__(256) void oproj_mfma_kernel(
        const u16* __restrict__ Ob, const u16* __restrict__ WoT,
        const float* __restrict__ bo, float* __restrict__ out) {
    gemm_mfma_body<1>(Ob, WoT, bo, nullptr, out);
}

// ---------------------------------------------------------------------------
// MFMA flash attention v3: NO-MAX softmax + cooperative LDS staging.
// Block = (64 Q rows, head); 4 waves share one tile list (identical for all
// waves except block 0). K/V tiles staged via global_load_lds (same swizzle
// as GEMM), double-buffered, 2-phase: stage(t+1) -> compute(t) -> barrier.
// XCD-chunked block swizzle: each XCD owns 2 heads -> K/V L2-resident.
// Block-0 waves guard COMPUTE (not staging) on their own band.
// ---------------------------------------------------------------------------
__global__ __launch_bounds__(256) void attn_mfma_kernel(
        const u16* __restrict__ Qb, const u16* __restrict__ Kb,
        const u16* __restrict__ VT, u16* __restrict__ Ob) {
    __shared__ __align__(16) u16 Ks[2][64 * 64];      // 16 KB
    __shared__ __align__(16) u16 Vs[2][64 * 64];      // 16 KB
    __shared__ __align__(16) u16 Pl[4 * 16 * 72];     // per-wave P, 9 KB
    const int tid = threadIdx.x;
    const int w = tid >> 6, l = tid & 63;
    const int l15 = l & 15, lh = l >> 4;

    // XCD-chunked swizzle (512 blocks = 8 XCDs x 64): XCD owns 2 whole heads
    const int swz = (blockIdx.x & 7) * 64 + (blockIdx.x >> 3);
    const int h = swz >> 5, i0 = (swz & 31) * 64;
    const int q0 = i0 + w * 16;
    u16* Pw = &Pl[w * 16 * 72];

    // Q A-frags: lane row l15, chunk ks*32 + lh*8
    bf16x8 qf[2];
    {
        int qr = q0 + l15;
        qf[0] = *(const bf16x8*)&Qb[qr * DM + h * DH + lh * 8];
        qf[1] = *(const bf16x8*)&Qb[qr * DM + h * DH + 32 + lh * 8];
    }

    f32x4 o[4];
    float ls[4] = {0.f, 0.f, 0.f, 0.f};
#pragma unroll
    for (int fc = 0; fc < 4; ++fc) o[fc] = (f32x4)0.f;

    // block-level tile list: band + appended global tile 0 (iff t_lo > 0)
    int t_lo, t_hi;
    {
        int lo = i0 - WIN;      if (lo < 0) lo = 0;
        int hi = i0 + 63 + WIN; if (hi > S_LEN - 1) hi = S_LEN - 1;
        if (i0 == 0) hi = S_LEN - 1;          // block 0: wave 0 holds global row 0
        t_lo = lo >> 6; t_hi = hi >> 6;
    }
    const int nband = t_hi - t_lo + 1;
    const int nt = nband + (t_lo > 0 ? 1 : 0);
    // this wave's own band end (for the block-0 compute guard)
    int wt_hi;
    {
        int whi = q0 + 15 + WIN; if (whi > S_LEN - 1) whi = S_LEN - 1;
        wt_hi = whi >> 6;
    }
    const bool isglob = (q0 == 0);

    // staging lane geometry (identical to GEMM): lane chunk g = (l&7)^(l>>3)
    const int lr = l >> 3, g = (l & 7) ^ lr;

    int cur = 0;
    // prologue: stage tile 0
    {
        const int j0 = t_lo << 6;
#pragma unroll
        for (int c2 = 0; c2 < 2; ++c2) {
            int c = w * 2 + c2;
            GLDS(&Kb[(size_t)(j0 + c * 8 + lr) * DM + h * DH + g * 8], &Ks[0][c * 512]);
            GLDS(&VT[(size_t)(h * DH + c * 8 + lr) * S_LEN + j0 + g * 8], &Vs[0][c * 512]);
        }
    }
    __syncthreads();

    for (int it = 0; it < nt; ++it) {
        const int t = (it < nband) ? (t_lo + it) : 0;
        const int j0 = t << 6;

        // stage next tile into the other buffer
        if (it + 1 < nt) {
            const int jn = ((it + 1 < nband) ? (t_lo + it + 1) : 0) << 6;
            u16* KsB = Ks[cur ^ 1];
            u16* VsB = Vs[cur ^ 1];
#pragma unroll
            for (int c2 = 0; c2 < 2; ++c2) {
                int c = w * 2 + c2;
                GLDS(&Kb[(size_t)(jn + c * 8 + lr) * DM + h * DH + g * 8], &KsB[c * 512]);
                GLDS(&VT[(size_t)(h * DH + c * 8 + lr) * S_LEN + jn + g * 8], &VsB[c * 512]);
            }
        }

        // compute guard: skip tiles fully outside this wave's band
        // (only differs from all-true in block 0; appended tile 0 = everyone)
        if (isglob || it >= nband || t <= wt_hi) {
            const u16* Kc = Ks[cur];
            const u16* Vc = Vs[cur];

            // S = Q K^T   (frag reads XOR-unswizzled, <=2-way)
            f32x4 s[4];
#pragma unroll
            for (int fc = 0; fc < 4; ++fc) s[fc] = (f32x4)0.f;
#pragma unroll
            for (int ks = 0; ks < 2; ++ks)
#pragma unroll
                for (int fc = 0; fc < 4; ++fc) {
                    int rb = fc * 16 + l15;
                    bf16x8 kf = *(const bf16x8*)&Kc[rb * 64 + (((ks * 4 + lh) ^ (rb & 7)) * 8)];
                    s[fc] = __builtin_amdgcn_mfma_f32_16x16x32_bf16(qf[ks], kf, s[fc], 0, 0, 0);
                }

            // mask + exp (no max-sub); lane-local row-sum accumulate
#pragma unroll
            for (int fc = 0; fc < 4; ++fc)
#pragma unroll
                for (int rr = 0; rr < 4; ++rr) {
                    int r = q0 + lh * 4 + rr;
                    int c = j0 + fc * 16 + l15;
                    int d = r - c;
                    bool ok = (d <= WIN && -d <= WIN) || (r == 0) || (c == 0);
                    s[fc][rr] = ok ? __expf(s[fc][rr] * 0.125f) : 0.f;
                }
#pragma unroll
            for (int rr = 0; rr < 4; ++rr)
                ls[rr] += (s[0][rr] + s[1][rr]) + (s[2][rr] + s[3][rr]);

            // P -> wave-private LDS as bf16 [qrow16][kv64], pitch 72
#pragma unroll
            for (int fc = 0; fc < 4; ++fc)
#pragma unroll
                for (int rr = 0; rr < 4; ++rr)
                    Pw[(lh * 4 + rr) * 72 + fc * 16 + l15] = f2bf(s[fc][rr]);
            asm volatile("s_waitcnt lgkmcnt(0)" ::: "memory");

            // O += P V
#pragma unroll
            for (int ks = 0; ks < 2; ++ks) {
                bf16x8 pa = *(const bf16x8*)&Pw[l15 * 72 + ks * 32 + lh * 8];
#pragma unroll
                for (int fc = 0; fc < 4; ++fc) {
                    int rb = fc * 16 + l15;
                    bf16x8 vfr = *(const bf16x8*)&Vc[rb * 64 + (((ks * 4 + lh) ^ (rb & 7)) * 8)];
                    o[fc] = __builtin_amdgcn_mfma_f32_16x16x32_bf16(pa, vfr, o[fc], 0, 0, 0);
                }
            }
        }

        __syncthreads();   // next-tile stage landed; all waves done with cur
        cur ^= 1;
    }

    // single cross-lane reduce of row sums (within each 16-lane lh group)
#pragma unroll
    for (int rr = 0; rr < 4; ++rr)
#pragma unroll
        for (int mk = 1; mk < 16; mk <<= 1)
            ls[rr] += __shfl_xor(ls[rr], mk, 64);

    // epilogue: /lsum, write bf16
#pragma unroll
    for (int rr = 0; rr < 4; ++rr) {
        float inv = 1.0f / ls[rr];
#pragma unroll
        for (int fc = 0; fc < 4; ++fc)
            Ob[(q0 + lh * 4 + rr) * DM + h * DH + fc * 16 + l15] = f2bf(o[fc][rr] * inv);
    }
}

// ---------------------------------------------------------------------------
extern "C" void kernel_launch(void* const* d_in, const int* in_sizes, int n_in,
                              void* d_out, int out_size, void* d_ws, size_t ws_size,
                              hipStream_t stream) {
    const float* x  = (const float*)d_in[0];
    const float* Wq = (const float*)d_in[1];
    const float* bq = (const float*)d_in[2];
    const float* Wk = (const float*)d_in[3];
    const float* bk = (const float*)d_in[4];
    const float* Wv = (const float*)d_in[5];
    const float* bv = (const float*)d_in[6];
    const float* Wo = (const float*)d_in[7];
    const float* bo = (const float*)d_in[8];
    float* out = (float*)d_out;

    char* W = (char*)d_ws;
    u16* xb  = (u16*)(W);                        // 4 MB  (reused as Ob after qkv)
    u16* WT  = (u16*)(W + ((size_t)4  << 20));   // 4 x 2 MB = 8 MB
    u16* Qb  = (u16*)(W + ((size_t)12 << 20));   // 4 MB
    u16* Kb  = (u16*)(W + ((size_t)16 << 20));   // 4 MB
    u16* VT  = (u16*)(W + ((size_t)20 << 20));   // 4 MB   (total 24 MB)
    u16* Ob  = xb;                               // x dead after qkv
    const u16* WqT = WT;
    const u16* WkT = WT + (1u << 20);
    const u16* WvT = WT + (2u << 20);
    const u16* WoT = WT + (3u << 20);

    cvt_x_kernel <<<dim3(S_LEN * DM / (256 * 8)), 256, 0, stream>>>(x, xb);
    cvt_wT_kernel<<<dim3(16, 16, 4), 256, 0, stream>>>(Wq, Wk, Wv, Wo, WT);
    qkv_mfma_kernel<<<dim3(8, 32, 3), 256, 0, stream>>>(xb, WqT, bq, Qb,
                                                        WkT, bk, Kb, WvT, bv, VT);
    attn_mfma_kernel<<<dim3(512), 256, 0, stream>>>(Qb, Kb, VT, Ob);
    oproj_mfma_kernel<<<dim3(8, 32), 256, 0, stream>>>(Ob, WoT, bo, out);
}